// Round 7
// baseline (122.944 us; speedup 1.0000x reference)
//
#include <hip/hip_runtime.h>
#include <hip/hip_bf16.h>

// LIF recurrence: v = tau*v + (1-tau)*x_t ; s = (v > vth) ; v -= s (vth=1, reset=0)
// B=64, T=256, U=1024 fp32.
//
// R2-R6 ledger: depth(16/32), width(dword/x2), store policy(nt/normal),
// store shape(interleaved/burst/LDS-transposed-wide) ALL neutral at ~26.4us
// = 128 MB combined @ 4.9 TB/s, vs 6.3 TB/s homogeneous ceiling (fill/copy).
// Last untested mechanism: DIRECTION SEGREGATION + bit compression.
//   K1: LIF compute, R2 load pipeline, spikes __ballot-packed to 1 bit
//       -> 64 MB read + 2 MB write (near-pure read stream).
//   K2: bit -> float expand, 2 MB read (LLC-hot) + 64 MB write
//       (fill-kernel profile, measured 6.38 TB/s every round).
// Packed layout ws_u64[b][u64][t] so K1 stores are 512 B/wave coalesced and
// K2 loads are same-line merged.
//
// Bit-exactness vs numpy fp32: non-fused __fmul_rn/__fadd_rn so the spike
// compare (v > 1.0f) sees identical rounding to the reference.

typedef float vfloat4 __attribute__((ext_vector_type(4)));

constexpr int kB = 64;
constexpr int kT = 256;
constexpr int kU = 1024;
constexpr int kG = 16;              // t-group size / load prefetch depth

// ---------- K1: LIF + bit-pack ----------
__global__ __launch_bounds__(256)
void lif_pack(const float* __restrict__ x, unsigned long long* __restrict__ ws) {
    const int idx  = blockIdx.x * blockDim.x + threadIdx.x;  // over B*U
    const int b    = idx >> 10;
    const int u    = idx & (kU - 1);
    const int lane = threadIdx.x & 63;
    const int u64i = u >> 6;                                 // wave-uniform

    const float* __restrict__ xp = x + (size_t)b * kT * kU + u;
    unsigned long long* __restrict__ wp = ws + ((size_t)b * 16 + u64i) * kT;

    float buf[kG], nbuf[kG];
#pragma unroll
    for (int j = 0; j < kG; ++j)
        buf[j] = xp[(size_t)j * kU];

    float v = 0.0f;
    unsigned long long myMask = 0;
    for (int g = 0; g < kT / kG; ++g) {
        const int t0 = g * kG;
        const bool more = (g + 1 < kT / kG);
        if (more) {
#pragma unroll
            for (int j = 0; j < kG; ++j)
                nbuf[j] = xp[(size_t)(t0 + kG + j) * kU];    // prefetch next group
        }
#pragma unroll
        for (int j = 0; j < kG; ++j) {
            const float a  = __fmul_rn(0.25f, v);
            const float cc = __fmul_rn(0.75f, buf[j]);
            v = __fadd_rn(a, cc);
            const bool pred = (v > 1.0f);
            v = __fsub_rn(v, pred ? 1.0f : 0.0f);
            const unsigned long long m = __ballot(pred);     // bit j = lane j = u%64
            if (lane == ((t0 + j) & 63)) myMask = m;         // lane L holds mask(t: t&63==L)
        }
        if ((g & 3) == 3) {
            // one coalesced 512 B store per wave per 64 timesteps
            wp[(g >> 2) * 64 + lane] = myMask;
        }
        if (more) {
#pragma unroll
            for (int j = 0; j < kG; ++j)
                buf[j] = nbuf[j];
        }
    }
}

// ---------- K2: bit -> float expand (fill-kernel profile) ----------
__global__ __launch_bounds__(256)
void lif_expand(const unsigned long long* __restrict__ ws, vfloat4* __restrict__ out) {
    const int f  = blockIdx.x * blockDim.x + threadIdx.x;    // float4 index
    const int u4 = f & 255;                                  // u/4
    const int t  = (f >> 8) & 255;
    const int b  = f >> 16;

    const unsigned long long w = ws[((size_t)b * 16 + (u4 >> 4)) * kT + t];
    const unsigned s = (unsigned)(w >> ((u4 & 15) * 4)) & 0xFu;
    vfloat4 o;
    o.x = (s & 1u) ? 1.0f : 0.0f;
    o.y = (s & 2u) ? 1.0f : 0.0f;
    o.z = (s & 4u) ? 1.0f : 0.0f;
    o.w = (s & 8u) ? 1.0f : 0.0f;
    out[f] = o;                                              // dwordx4, coalesced
}

// ---------- fallback: R2's proven single kernel (if ws too small) ----------
__global__ __launch_bounds__(256)
void lif_kernel(const float* __restrict__ x, float* __restrict__ out) {
    const int idx = blockIdx.x * blockDim.x + threadIdx.x;
    const int b = idx >> 10;
    const int u = idx & (kU - 1);
    const size_t base = (size_t)b * kT * kU + u;
    const float* __restrict__ xp = x + base;
    float* __restrict__ op = out + base;

    float buf[kG], nbuf[kG];
#pragma unroll
    for (int j = 0; j < kG; ++j)
        buf[j] = xp[(size_t)j * kU];

    float v = 0.0f;
    for (int g = 0; g < kT / kG; ++g) {
        const int t0 = g * kG;
        const bool more = (g + 1 < kT / kG);
        if (more) {
#pragma unroll
            for (int j = 0; j < kG; ++j)
                nbuf[j] = xp[(size_t)(t0 + kG + j) * kU];
        }
#pragma unroll
        for (int j = 0; j < kG; ++j) {
            const float a  = __fmul_rn(0.25f, v);
            const float cc = __fmul_rn(0.75f, buf[j]);
            v = __fadd_rn(a, cc);
            const float s = (v > 1.0f) ? 1.0f : 0.0f;
            v = __fsub_rn(v, s);
            op[(size_t)(t0 + j) * kU] = s;
        }
        if (more) {
#pragma unroll
            for (int j = 0; j < kG; ++j)
                buf[j] = nbuf[j];
        }
    }
}

extern "C" void kernel_launch(void* const* d_in, const int* in_sizes, int n_in,
                              void* d_out, int out_size, void* d_ws, size_t ws_size,
                              hipStream_t stream) {
    const float* x = (const float*)d_in[0];
    const size_t packedBytes = (size_t)kB * kT * kU / 8;     // 2 MiB

    if (ws_size >= packedBytes) {
        unsigned long long* ws = (unsigned long long*)d_ws;
        lif_pack<<<kB * kU / 256, 256, 0, stream>>>(x, ws);
        lif_expand<<<kB * kT * kU / 4 / 256, 256, 0, stream>>>(ws, (vfloat4*)d_out);
    } else {
        lif_kernel<<<kB * kU / 256, 256, 0, stream>>>(x, (float*)d_out);
    }
}